// Round 11
// baseline (284.770 us; speedup 1.0000x reference)
//
#include <hip/hip_runtime.h>
#include <math.h>

#define NN 4096
#define DD 256
#define KK 3
#define RR 32
#define MAXNNZ 128

static constexpr float ETA    = 0.5f;
static constexpr float COEFF  = 0.03125f;   // R/(N*eps^2) = 32/(4096*0.25)
static constexpr float LN_EPSF = 1e-5f;

// workspace layout (float offsets)
#define OFF_H1   0
#define OFF_H2   (NN*DD)
#define OFF_H3   (2*NN*DD)
#define OFF_Y    (3*NN*DD)
#define OFF_P    (OFF_Y + KK*NN*RR)
#define OFF_M    (OFF_P + KK*NN*RR)
#define OFF_MINV (OFF_M + KK*RR*RR)
#define OFF_SCAL (OFF_MINV + KK*RR*RR)   // w[3], laps[3]
#define OFF_NNZ  (OFF_SCAL + 8)          // N ints
#define OFF_COLS (OFF_NNZ + NN)          // N*MAXNNZ ints
#define OFF_VALS (OFF_COLS + NN*MAXNNZ)  // N*MAXNNZ floats
#define OFF_PART (OFF_VALS + NN*MAXNNZ)  // NN/4 floats (lap_smooth partials)
#define OFF_ORTH (OFF_PART + NN/4)       // 6 floats (orth partials)
#define OFF_W    (OFF_ORTH + 8)          // KK*DD*RR floats: W_k = U_k @ Minv_k

// ---------------- dispatch 1: CSR extract + FUSED H1/Y0/Y1 + orth + prep ----------------
// R8: A-scan is pattern-floor-bound (~41us regardless of structure), so this kernel does
// more per byte: CSR -> LDS -> H1 = A@H -> Y0/Y1 projections, removing a whole spmv
// dispatch. R10 LESSON: splitting the row gather across 2 waves reassociated the H1 sum
// and DOUBLED absmax (0.0078->0.0156) for zero perf — phase 3 stays waves 0/2 only,
// bit-identical to the unfused spmv ordering.
__global__ __launch_bounds__(256, 4)
void k_csr_prep(const float* __restrict__ A, int* __restrict__ nnz,
                int* __restrict__ cols, float* __restrict__ vals,
                const float* __restrict__ hw, const float* __restrict__ ll,
                const float* __restrict__ U,
                float* __restrict__ ws, float* __restrict__ out,
                const float* __restrict__ H) {
  int b = blockIdx.x;
  int t = threadIdx.x;
  if (b >= NN/2) {
    int p = b - NN/2;
    if (p == 6) {
      if (t == 0) {
        float m = fmaxf(fmaxf(hw[0], hw[1]), hw[2]);
        float e0 = expf(hw[0]-m), e1 = expf(hw[1]-m), e2 = expf(hw[2]-m);
        float s = e0 + e1 + e2;
        float w0 = e0/s, w1 = e1/s, w2 = e2/s;
        ws[OFF_SCAL+0] = w0; ws[OFF_SCAL+1] = w1; ws[OFF_SCAL+2] = w2;
        for (int k = 0; k < KK; ++k) {
          float x = ll[k];
          ws[OFF_SCAL+3+k] = (x > 20.f) ? x : log1pf(expf(x));
        }
        out[NN*DD + 2] = w0; out[NN*DD + 3] = w1; out[NN*DD + 4] = w2;  // w output
      }
      for (int idx = t; idx < KK*RR*RR; idx += 256) {
        int rr2 = idx % (RR*RR);
        ws[OFF_M + idx] = ((rr2 / RR) == (rr2 % RR)) ? 1.f : 0.f;
      }
      return;
    }
    // orth pair p: thread owns 4 cells (same col bb, rows a0, a0+8, a0+16, a0+24)
    int k = (p < 3) ? 0 : ((p < 5) ? 1 : 2);
    int l = (p < 3) ? p : ((p < 5) ? p - 2 : 2);
    int a0 = t >> 5, bb = t & 31;
    float s0 = 0.f, s1 = 0.f, s2 = 0.f, s3 = 0.f;
    for (int dd = 0; dd < DD; ++dd) {
      float ul = U[(size_t)l*DD*RR + dd*RR + bb];
      const float* uk = U + (size_t)k*DD*RR + dd*RR;
      s0 += uk[a0]      * ul;
      s1 += uk[a0 + 8]  * ul;
      s2 += uk[a0 + 16] * ul;
      s3 += uk[a0 + 24] * ul;
    }
    if (k == l && bb == a0)      s0 -= 1.f;
    if (k == l && bb == a0 + 8)  s1 -= 1.f;
    if (k == l && bb == a0 + 16) s2 -= 1.f;
    if (k == l && bb == a0 + 24) s3 -= 1.f;
    float sq = s0*s0 + s1*s1 + s2*s2 + s3*s3;
    #pragma unroll
    for (int o = 32; o > 0; o >>= 1) sq += __shfl_xor(sq, o, 64);
    __shared__ float red[4];
    if ((t & 63) == 0) red[t >> 6] = sq;
    __syncthreads();
    if (t == 0) ws[OFF_ORTH + p] = red[0] + red[1] + red[2] + red[3];
    return;
  }
  // ---- phase 1: scan. wave w = (row r = w>>1, half h2 = w&1). Half = 2048 cols. ----
  int w = t >> 6, lane = t & 63;
  int r = w >> 1, h2 = w & 1;
  int i = b * 2 + r;
  __shared__ int   cbuf[2][2][MAXNNZ];
  __shared__ float vbuf[2][2][MAXNNZ];
  __shared__ int   csr_c[2][MAXNNZ];
  __shared__ float csr_v[2][MAXNNZ];
  __shared__ int   cnts[4];
  __shared__ int   nnzs[2];
  __shared__ float Hs[2][2][DD];   // [row][0=own(H),1=acc(H1)][dim]
  const float4* row4 = (const float4*)(A + (size_t)i * NN);
  float4 vv[8];
  #pragma unroll
  for (int it = 0; it < 8; ++it) vv[it] = row4[h2*512 + it*64 + lane];  // 8 loads in flight
  unsigned long long lower = lane ? (~0ull >> (64 - lane)) : 0ull;
  int base = 0;
  #pragma unroll
  for (int it = 0; it < 8; ++it) {
    float4 v = vv[it];
    int jb = (h2*512 + it*64 + lane) * 4;
    unsigned long long mx = __ballot(v.x != 0.f);
    unsigned long long my = __ballot(v.y != 0.f);
    unsigned long long mz = __ballot(v.z != 0.f);
    unsigned long long mw = __ballot(v.w != 0.f);
    int before = __popcll(mx & lower) + __popcll(my & lower)
               + __popcll(mz & lower) + __popcll(mw & lower);
    int p0 = base + before;
    int bx = (mx >> lane) & 1, by = (my >> lane) & 1, bz = (mz >> lane) & 1;
    if (v.x != 0.f && p0 < MAXNNZ)  { cbuf[r][h2][p0] = jb;   vbuf[r][h2][p0] = v.x; }
    int p1 = p0 + bx;
    if (v.y != 0.f && p1 < MAXNNZ)  { cbuf[r][h2][p1] = jb+1; vbuf[r][h2][p1] = v.y; }
    int p2 = p1 + by;
    if (v.z != 0.f && p2 < MAXNNZ)  { cbuf[r][h2][p2] = jb+2; vbuf[r][h2][p2] = v.z; }
    int p3 = p2 + bz;
    if (v.w != 0.f && p3 < MAXNNZ)  { cbuf[r][h2][p3] = jb+3; vbuf[r][h2][p3] = v.w; }
    base += __popcll(mx) + __popcll(my) + __popcll(mz) + __popcll(mw);
  }
  if (lane == 0) cnts[w] = base < MAXNNZ ? base : MAXNNZ;
  __syncthreads();
  // ---- phase 2: merge to global CSR AND LDS CSR ----
  {
    int rr = t >> 7, e0 = t & 127;
    int ii = b * 2 + rr;
    int n0 = cnts[rr*2], n1 = cnts[rr*2 + 1];
    int n = n0 + n1; if (n > MAXNNZ) n = MAXNNZ;
    int npad = (n + 7) & ~7;
    for (int e = e0; e < npad; e += 128) {
      int c; float v;
      if (e < n) {
        if (e < n0) { c = cbuf[rr][0][e];      v = vbuf[rr][0][e]; }
        else        { c = cbuf[rr][1][e - n0]; v = vbuf[rr][1][e - n0]; }
      } else { c = ii; v = 0.f; }
      cols[ii*MAXNNZ + e] = c;
      vals[ii*MAXNNZ + e] = v;
      csr_c[rr][e] = c;
      csr_v[rr][e] = v;
    }
    if (e0 == 0) { nnz[ii] = n; nnzs[rr] = n; }
  }
  __syncthreads();
  // ---- phase 3: H1 = A@H for this block's 2 rows (waves 0,2; CSR from LDS) ----
  float* H1 = ws + OFF_H1;
  if ((w & 1) == 0) {
    int rI = w >> 1;
    int row = b * 2 + rI;
    int d4 = lane * 4;
    int n2 = nnzs[rI], npad2 = (n2 + 7) & ~7;
    float4 acc = {0.f, 0.f, 0.f, 0.f};
    float4 own = {0.f, 0.f, 0.f, 0.f};
    for (int e0i = 0; e0i < npad2; e0i += 8) {
      int4 c0 = *(const int4*)&csr_c[rI][e0i];
      int4 c1 = *(const int4*)&csr_c[rI][e0i + 4];
      float4 v0 = *(const float4*)&csr_v[rI][e0i];
      float4 v1 = *(const float4*)&csr_v[rI][e0i + 4];
      float4 x0 = *(const float4*)(H + (size_t)c0.x*DD + d4);
      float4 x1 = *(const float4*)(H + (size_t)c0.y*DD + d4);
      float4 x2 = *(const float4*)(H + (size_t)c0.z*DD + d4);
      float4 x3 = *(const float4*)(H + (size_t)c0.w*DD + d4);
      float4 x4 = *(const float4*)(H + (size_t)c1.x*DD + d4);
      float4 x5 = *(const float4*)(H + (size_t)c1.y*DD + d4);
      float4 x6 = *(const float4*)(H + (size_t)c1.z*DD + d4);
      float4 x7 = *(const float4*)(H + (size_t)c1.w*DD + d4);
      if (c0.x == row) own = x0;
      if (c0.y == row) own = x1;
      if (c0.z == row) own = x2;
      if (c0.w == row) own = x3;
      if (c1.x == row) own = x4;
      if (c1.y == row) own = x5;
      if (c1.z == row) own = x6;
      if (c1.w == row) own = x7;
      acc.x += v0.x*x0.x + v0.y*x1.x + v0.z*x2.x + v0.w*x3.x + v1.x*x4.x + v1.y*x5.x + v1.z*x6.x + v1.w*x7.x;
      acc.y += v0.x*x0.y + v0.y*x1.y + v0.z*x2.y + v0.w*x3.y + v1.x*x4.y + v1.y*x5.y + v1.z*x6.y + v1.w*x7.y;
      acc.z += v0.x*x0.z + v0.y*x1.z + v0.z*x2.z + v0.w*x3.z + v1.x*x4.z + v1.y*x5.z + v1.z*x6.z + v1.w*x7.z;
      acc.w += v0.x*x0.w + v0.y*x1.w + v0.z*x2.w + v0.w*x3.w + v1.x*x4.w + v1.y*x5.w + v1.z*x6.w + v1.w*x7.w;
    }
    *(float4*)(H1 + (size_t)row*DD + d4) = acc;
    *(float4*)&Hs[rI][0][d4] = own;
    *(float4*)&Hs[rI][1][d4] = acc;
  }
  __syncthreads();
  // ---- phase 4: projections. wave w -> (row w>>1, w&1 ? Y1=H1@U1 : Y0=H@U0) ----
  {
    int rI = w >> 1;
    int row = b * 2 + rI;
    int useAcc = w & 1;
    const float* Up = U + (size_t)useAcc*DD*RR;          // U0 or U1
    float* Yp = ws + OFF_Y + (size_t)useAcc*NN*RR;       // Y0 or Y1
    int c = lane & 31, h = lane >> 5;
    float part = 0.f;
    #pragma unroll 8
    for (int d = h*128; d < h*128 + 128; ++d) part += Hs[rI][useAcc][d] * Up[d*RR + c];
    part += __shfl_xor(part, 32, 64);
    if (h == 0) Yp[(size_t)row*RR + c] = part;
  }
}

// ---------------- 4-row sparse gather quad: acc = (A @ X)[row], own = X[row] ------------
__device__ __forceinline__ void spmv_quad(const float* __restrict__ X, int row, int lane,
                                          const int* __restrict__ nnz,
                                          const int* __restrict__ cols,
                                          const float* __restrict__ vals,
                                          float4& acc, float4& own) {
  int d4 = lane * 4;
  int n = nnz[row];
  int npad = (n + 7) & ~7;
  const int* ci = cols + row*MAXNNZ;
  const float* vi = vals + row*MAXNNZ;
  for (int e0 = 0; e0 < npad; e0 += 8) {
    int4 c0 = *(const int4*)(ci + e0);
    int4 c1 = *(const int4*)(ci + e0 + 4);
    float4 v0 = *(const float4*)(vi + e0);
    float4 v1 = *(const float4*)(vi + e0 + 4);
    float4 x0 = *(const float4*)(X + (size_t)c0.x*DD + d4);
    float4 x1 = *(const float4*)(X + (size_t)c0.y*DD + d4);
    float4 x2 = *(const float4*)(X + (size_t)c0.z*DD + d4);
    float4 x3 = *(const float4*)(X + (size_t)c0.w*DD + d4);
    float4 x4 = *(const float4*)(X + (size_t)c1.x*DD + d4);
    float4 x5 = *(const float4*)(X + (size_t)c1.y*DD + d4);
    float4 x6 = *(const float4*)(X + (size_t)c1.z*DD + d4);
    float4 x7 = *(const float4*)(X + (size_t)c1.w*DD + d4);
    if (c0.x == row) own = x0;
    if (c0.y == row) own = x1;
    if (c0.z == row) own = x2;
    if (c0.w == row) own = x3;
    if (c1.x == row) own = x4;
    if (c1.y == row) own = x5;
    if (c1.z == row) own = x6;
    if (c1.w == row) own = x7;
    acc.x += v0.x*x0.x + v0.y*x1.x + v0.z*x2.x + v0.w*x3.x + v1.x*x4.x + v1.y*x5.x + v1.z*x6.x + v1.w*x7.x;
    acc.y += v0.x*x0.y + v0.y*x1.y + v0.z*x2.y + v0.w*x3.y + v1.x*x4.y + v1.y*x5.y + v1.z*x6.y + v1.w*x7.y;
    acc.z += v0.x*x0.z + v0.y*x1.z + v0.z*x2.z + v0.w*x3.z + v1.x*x4.z + v1.y*x5.z + v1.z*x6.z + v1.w*x7.z;
    acc.w += v0.x*x0.w + v0.y*x1.w + v0.z*x2.w + v0.w*x3.w + v1.x*x4.w + v1.y*x5.w + v1.z*x6.w + v1.w*x7.w;
  }
}

// ---------------- sparse A @ X with fused Y projection + gram(k=0,1) extra blocks --------
// EXTRA BLOCKS (x >= NN/4): 256-thread Gram blocks for k=0,1 (Y0/Y1 complete after
// dispatch 1; overlaps the H2 spmv which touches neither Y0/Y1 nor M). Per-cell i-loop
// order identical to the old 1024-thread k_gram -> cell results bit-identical; atomicAdd
// arrival order was already nondeterministic.
__global__ void k_spmvy(const float* __restrict__ X, float* __restrict__ Hout,
                        const int* __restrict__ nnz, const int* __restrict__ cols,
                        const float* __restrict__ vals,
                        const float* __restrict__ Uo, float* __restrict__ Yo,
                        const float* __restrict__ Un, float* __restrict__ Yn,
                        const float* __restrict__ Yg, float* __restrict__ Mg) {
  int t = threadIdx.x;
  if (blockIdx.x >= NN/4) {
    if (!Yg) return;
    int gb = blockIdx.x - NN/4;          // 0..63: k = gb>>5, row-chunk g = gb&31
    int k = gb >> 5, g = gb & 31;
    __shared__ float Ys[128*RR];
    const float* Yk = Yg + (size_t)k*NN*RR + (size_t)g*128*RR;
    for (int idx = t; idx < 128*RR; idx += 256) Ys[idx] = Yk[idx];
    __syncthreads();
    int a = t >> 3, b4 = (t & 7) * 4;    // 4 cells per thread
    float s0 = 0.f, s1 = 0.f, s2 = 0.f, s3 = 0.f;
    for (int i = 0; i < 128; ++i) {
      float ya = Ys[i*RR + a];
      s0 += ya * Ys[i*RR + b4];
      s1 += ya * Ys[i*RR + b4 + 1];
      s2 += ya * Ys[i*RR + b4 + 2];
      s3 += ya * Ys[i*RR + b4 + 3];
    }
    atomicAdd(&Mg[k*RR*RR + a*RR + b4],     COEFF * s0);
    atomicAdd(&Mg[k*RR*RR + a*RR + b4 + 1], COEFF * s1);
    atomicAdd(&Mg[k*RR*RR + a*RR + b4 + 2], COEFF * s2);
    atomicAdd(&Mg[k*RR*RR + a*RR + b4 + 3], COEFF * s3);
    return;
  }
  int r = t >> 6, lane = t & 63;
  int row = blockIdx.x * 4 + r;
  int d4 = lane * 4;
  float4 acc = {0.f, 0.f, 0.f, 0.f};
  float4 own = {0.f, 0.f, 0.f, 0.f};
  spmv_quad(X, row, lane, nnz, cols, vals, acc, own);
  *(float4*)(Hout + (size_t)row*DD + d4) = acc;
  if (!Uo && !Un) return;
  __shared__ float Hs[4][2][DD];
  *(float4*)&Hs[r][0][d4] = own;
  *(float4*)&Hs[r][1][d4] = acc;
  __syncthreads();
  int c = lane & 31, h = lane >> 5;
  if (Uo) {
    float part = 0.f;
    #pragma unroll 8
    for (int d = h*128; d < h*128 + 128; ++d) part += Hs[r][0][d] * Uo[d*RR + c];
    part += __shfl_xor(part, 32, 64);
    if (h == 0) Yo[(size_t)row*RR + c] = part;
  }
  if (Un) {
    float part = 0.f;
    #pragma unroll 8
    for (int d = h*128; d < h*128 + 128; ++d) part += Hs[r][1][d] * Un[d*RR + c];
    part += __shfl_xor(part, 32, 64);
    if (h == 0) Yn[(size_t)row*RR + c] = part;
  }
}

// ---------------- gram k=2 (blocks 0..31) + H3 = A@H2 spmv (blocks 32..) -----------------
// gram2's 32 blocks leave 87% of the GPU idle — the H3 gather (consumed only by k_epi)
// fills it for free. R5 showed H3-in-attn competes with attn blocks (neutral); here the
// overlap partner is near-empty. Per-cell gram i-loop order identical to the 1024-thread
// version -> bit-identical cells; H3 via unchanged spmv_quad -> bit-identical.
__global__ __launch_bounds__(256) void k_gram2h3(const float* __restrict__ Yk2, float* __restrict__ Mk2,
                                                 const int* __restrict__ nnz, const int* __restrict__ cols,
                                                 const float* __restrict__ vals,
                                                 const float* __restrict__ H2, float* __restrict__ H3) {
  int t = threadIdx.x;
  if (blockIdx.x < 32) {
    __shared__ float Ys[128*RR];
    const float* Yb = Yk2 + (size_t)blockIdx.x*128*RR;
    for (int idx = t; idx < 128*RR; idx += 256) Ys[idx] = Yb[idx];
    __syncthreads();
    int a = t >> 3, b4 = (t & 7) * 4;    // 4 cells per thread
    float s0 = 0.f, s1 = 0.f, s2 = 0.f, s3 = 0.f;
    for (int i = 0; i < 128; ++i) {
      float ya = Ys[i*RR + a];
      s0 += ya * Ys[i*RR + b4];
      s1 += ya * Ys[i*RR + b4 + 1];
      s2 += ya * Ys[i*RR + b4 + 2];
      s3 += ya * Ys[i*RR + b4 + 3];
    }
    atomicAdd(&Mk2[a*RR + b4],     COEFF * s0);
    atomicAdd(&Mk2[a*RR + b4 + 1], COEFF * s1);
    atomicAdd(&Mk2[a*RR + b4 + 2], COEFF * s2);
    atomicAdd(&Mk2[a*RR + b4 + 3], COEFF * s3);
    return;
  }
  int w = t >> 6, lane = t & 63;
  int row = (blockIdx.x - 32) * 4 + w;
  float4 acc = {0.f, 0.f, 0.f, 0.f};
  float4 own;
  spmv_quad(H2, row, lane, nnz, cols, vals, acc, own);
  *(float4*)(H3 + (size_t)row*DD + lane*4) = acc;
}

// ---------------- 32x32 inverse: rolled wave-synchronous LDS Gauss-Jordan ----------------
// One wave, zero barriers in the loop, ~150-instr body (icache-friendly). Lane t owns
// column t of the augmented [M | I] in LDS. Per pivot p: batch-read all 32 factors
// B[r][p] as independent broadcast reads BEFORE any write (pipelined). Grid (KK, 4):
// inverse computed redundantly per block; W = U @ Minv epilogue distributed over 4 blocks.
__global__ __launch_bounds__(256) void k_gj(const float* __restrict__ M, float* __restrict__ Minv,
                                            const float* __restrict__ U, float* __restrict__ W) {
  int k = blockIdx.x;
  int g = blockIdx.y;
  int t = threadIdx.x;
  __shared__ float B[RR][2*RR + 1];   // augmented [M | I], pad col to break bank patterns
  for (int idx = t; idx < RR*2*RR; idx += 256) {
    int r = idx >> 6, c = idx & 63;
    B[r][c] = (c < RR) ? M[k*RR*RR + r*RR + c] : ((c - RR == r) ? 1.f : 0.f);
  }
  __syncthreads();
  if (t < 64) {
    for (int p = 0; p < RR; ++p) {
      float rd = 1.f / B[p][p];       // broadcast read, all lanes same addr
      float pb = B[p][t] * rd;
      float f[RR];
      #pragma unroll
      for (int r = 0; r < RR; ++r) f[r] = B[r][p];   // 32 independent broadcast reads
      B[p][t] = pb;
      #pragma unroll
      for (int r = 0; r < RR; ++r) {
        if (r == p) continue;
        B[r][t] -= f[r] * pb;         // independent RMWs across r, pipelined
      }
    }
  }
  __syncthreads();
  if (g == 0)
    for (int idx = t; idx < RR*RR; idx += 256)
      Minv[k*RR*RR + idx] = B[idx >> 5][RR + (idx & 31)];
  // W_k[d][r] = sum_a U_k[d][a] * Minv[a][r], slice d in [g*64, g*64+64)
  for (int e = 0; e < 8; ++e) {
    int idx = t + e*256;              // 0..2047 within slice
    int d = g*64 + (idx >> 5), rr2 = idx & 31;
    const float* ud = U + (size_t)k*DD*RR + (size_t)d*RR;
    float s = 0.f;
    #pragma unroll
    for (int a = 0; a < RR; ++a) s += ud[a] * B[a][RR + rr2];
    W[(size_t)k*DD*RR + (size_t)d*RR + rr2] = s;
  }
}

// ---------------- sparse masked attention: P_i = sum_j alpha_ij Y_j (vsum only) ----------
// 4 rows per 256-thread block share one Minv LDS load. Pass 1 uses 4 lanes per neighbor
// AND spills each neighbor row to an LDS cache Yc[w][e][.] (stride 33: both write and
// read <=2-way bank aliasing -> free per m136). Pass 2 reads the cache instead of
// re-gathering the same rows from L2. Values/order bitwise-identical to uncached.
__global__ __launch_bounds__(256) void k_attn(const float* __restrict__ Y, const float* __restrict__ Minv,
                       float* __restrict__ P, const int* __restrict__ nnz,
                       const int* __restrict__ cols) {
  int k = blockIdx.y;
  int t = threadIdx.x;
  int w = t >> 6, lane = t & 63;       // wave w owns row i
  int i = blockIdx.x * 4 + w;
  const float* Yk = Y + (size_t)k*NN*RR;
  __shared__ float Mi[RR*RR];          // Minv (symmetric), shared by all 4 rows
  __shared__ float Yi[4][RR];
  __shared__ float qv[4][RR];
  __shared__ float sc[4][MAXNNZ];
  __shared__ float Yc[4][32][RR + 1];  // neighbor-row cache (e < 32), wave-private slices
  for (int idx = t; idx < RR*RR; idx += 256) Mi[idx] = Minv[k*RR*RR + idx];
  if (lane < RR) Yi[w][lane] = Yk[(size_t)i*RR + lane];
  sc[w][lane] = -1e30f; sc[w][lane+64] = -1e30f;
  __syncthreads();
  if (lane < RR) {
    float s = 0.f;
    #pragma unroll 8
    for (int a = 0; a < RR; ++a) s += Mi[a*RR + lane] * Yi[w][a];   // symmetric: col == row
    qv[w][lane] = s;
  }
  // wave-private from here on; no block barriers.
  int g = lane >> 2, a4 = lane & 3;
  const float* qq = &qv[w][8*a4];
  float q0 = qq[0], q1 = qq[1], q2 = qq[2], q3 = qq[3];
  float q4 = qq[4], q5 = qq[5], q6 = qq[6], q7 = qq[7];
  int n = nnz[i], npad = (n + 7) & ~7;
  const int* ci = cols + i*MAXNNZ;
  for (int e0 = 0; e0 < npad; e0 += 16) {
    int e = e0 + g;
    int ee = (e < npad) ? e : 0;
    int col = ci[ee];
    const float4* yr = (const float4*)(Yk + (size_t)col*RR + 8*a4);
    float4 y0 = yr[0], y1 = yr[1];
    if (e < 32) {                      // spill row quarter to cache (always true in practice)
      *(float4*)&Yc[w][e][8*a4]     = y0;
      *(float4*)&Yc[w][e][8*a4 + 4] = y1;
    }
    float s = y0.x*q0 + y0.y*q1 + y0.z*q2 + y0.w*q3
            + y1.x*q4 + y1.y*q5 + y1.z*q6 + y1.w*q7;
    s += __shfl_xor(s, 1, 64);
    s += __shfl_xor(s, 2, 64);
    if (a4 == 0 && e < npad) sc[w][e] = (e < n) ? s : -1e30f;
  }
  float s0 = sc[w][lane], s1 = sc[w][lane+64];
  float m = fmaxf(s0, s1);
  #pragma unroll
  for (int o = 32; o > 0; o >>= 1) m = fmaxf(m, __shfl_xor(m, o, 64));
  float e0v = expf(s0 - m), e1v = expf(s1 - m);
  sc[w][lane] = e0v; sc[w][lane+64] = e1v;
  float l = e0v + e1v;
  #pragma unroll
  for (int o = 32; o > 0; o >>= 1) l += __shfl_xor(l, o, 64);
  float linv = 1.f / l;
  int c = lane & 31, h = lane >> 5;
  float acc = 0.f;
  int lim = npad < 32 ? npad : 32;
  for (int e = h; e < lim; e += 2) acc += sc[w][e] * Yc[w][e][c];        // LDS, conflict-free
  for (int e = 32 + h; e < npad; e += 2) acc += sc[w][e] * Yk[(size_t)ci[e]*RR + c];  // rare tail
  acc += __shfl_xor(acc, 32, 64);
  if (lane < RR) P[(size_t)k*NN*RR + (size_t)i*RR + lane] = acc * linv;
}

// ---------------- fused epilogue (grad = W @ vsum) ----------------
__global__ void k_epi(const float* __restrict__ H0, const float* __restrict__ ws,
                      const float* __restrict__ thr,
                      const float* __restrict__ gma, const float* __restrict__ bta,
                      float* __restrict__ out) {
  __shared__ float Us[DD][RR+1];
  __shared__ float Ps[8][KK*RR];
  int t = threadIdx.x;
  int ty = t >> 5, tx = t & 31;
  int row0 = blockIdx.x * 8;
  const float* P    = ws + OFF_P;
  const float* scal = ws + OFF_SCAL;
  const float* W    = ws + OFF_W;
  for (int idx = t; idx < 8*KK*RR; idx += 256) {
    int rl = idx / (KK*RR), kr = idx % (KK*RR);
    int k = kr / RR, rr2 = kr % RR;
    Ps[rl][kr] = P[(size_t)k*NN*RR + (size_t)(row0+rl)*RR + rr2];
  }
  float lp0 = scal[3], lp1 = scal[4], lp2 = scal[5];
  float gacc[8];
  #pragma unroll
  for (int j = 0; j < 8; ++j) gacc[j] = 0.f;
  for (int k = 0; k < KK; ++k) {
    __syncthreads();
    // float4 W staging (2048 float4s per k, 8 per thread)
    for (int idx = t; idx < DD*RR/4; idx += 256) {
      float4 w4 = *(const float4*)(W + (size_t)k*DD*RR + (size_t)idx*4);
      int d = (idx*4) >> 5, c = (idx*4) & 31;
      Us[d][c] = w4.x; Us[d][c+1] = w4.y; Us[d][c+2] = w4.z; Us[d][c+3] = w4.w;
    }
    __syncthreads();
    float wk = scal[k];
    #pragma unroll
    for (int j = 0; j < 8; ++j) {
      int d = tx + 32*j;
      float s = 0.f;
      #pragma unroll
      for (int rr2 = 0; rr2 < RR; ++rr2) s += Ps[ty][k*RR + rr2] * Us[d][rr2];
      gacc[j] += wk * s;
    }
  }
  int i = row0 + ty;
  const float* H1 = ws + OFF_H1;
  const float* H2 = ws + OFF_H2;
  const float* H3 = ws + OFF_H3;
  float v[8]; float sum = 0.f, sumsq = 0.f;
  #pragma unroll
  for (int j = 0; j < 8; ++j) {
    int d = tx + 32*j;
    size_t idx = (size_t)i*DD + d;
    float h0 = H0[idx], h1 = H1[idx], h2 = H2[idx], h3 = H3[idx];
    float lap = lp0*(h0-h1) + lp1*(h1-h2) + lp2*(h2-h3);
    float hf = h0 + ETA*gacc[j] - ETA*lap;
    float a = fabsf(hf) - thr[d];
    float sft = (a > 0.f) ? copysignf(a, hf) : 0.f;
    float x = sft + h0;
    v[j] = x; sum += x; sumsq += x*x;
  }
  #pragma unroll
  for (int o = 16; o > 0; o >>= 1) {
    sum   += __shfl_xor(sum, o, 32);
    sumsq += __shfl_xor(sumsq, o, 32);
  }
  float mu  = sum * (1.f/DD);
  float var = sumsq * (1.f/DD) - mu*mu;
  float inv = rsqrtf(var + LN_EPSF);
  #pragma unroll
  for (int j = 0; j < 8; ++j) {
    int d = tx + 32*j;
    out[(size_t)i*DD + d] = (v[j] - mu) * inv * gma[d] + bta[d];
  }
}

// ---------------- lap_smooth partials (no fences, no atomics) ----------------
__global__ void k_lapsm(const float* __restrict__ Hout, const int* __restrict__ nnz,
                        const int* __restrict__ cols, const float* __restrict__ vals,
                        float* __restrict__ partial) {
  int t = threadIdx.x;
  int row = blockIdx.x * 4 + (t >> 6);
  int d4 = (t & 63) * 4;
  int n = nnz[row];
  int npad = (n + 7) & ~7;
  const int* ci = cols + row*MAXNNZ;
  const float* vi = vals + row*MAXNNZ;
  float4 acc = {0.f, 0.f, 0.f, 0.f};
  for (int e0 = 0; e0 < npad; e0 += 8) {
    int4 c0 = *(const int4*)(ci + e0);
    int4 c1 = *(const int4*)(ci + e0 + 4);
    float4 v0 = *(const float4*)(vi + e0);
    float4 v1 = *(const float4*)(vi + e0 + 4);
    float4 x0 = *(const float4*)(Hout + (size_t)c0.x*DD + d4);
    float4 x1 = *(const float4*)(Hout + (size_t)c0.y*DD + d4);
    float4 x2 = *(const float4*)(Hout + (size_t)c0.z*DD + d4);
    float4 x3 = *(const float4*)(Hout + (size_t)c0.w*DD + d4);
    float4 x4 = *(const float4*)(Hout + (size_t)c1.x*DD + d4);
    float4 x5 = *(const float4*)(Hout + (size_t)c1.y*DD + d4);
    float4 x6 = *(const float4*)(Hout + (size_t)c1.z*DD + d4);
    float4 x7 = *(const float4*)(Hout + (size_t)c1.w*DD + d4);
    acc.x += v0.x*x0.x + v0.y*x1.x + v0.z*x2.x + v0.w*x3.x + v1.x*x4.x + v1.y*x5.x + v1.z*x6.x + v1.w*x7.x;
    acc.y += v0.x*x0.y + v0.y*x1.y + v0.z*x2.y + v0.w*x3.y + v1.x*x4.y + v1.y*x5.y + v1.z*x6.y + v1.w*x7.y;
    acc.z += v0.x*x0.z + v0.y*x1.z + v0.z*x2.z + v0.w*x3.z + v1.x*x4.z + v1.y*x5.z + v1.z*x6.z + v1.w*x7.z;
    acc.w += v0.x*x0.w + v0.y*x1.w + v0.z*x2.w + v0.w*x3.w + v1.x*x4.w + v1.y*x5.w + v1.z*x6.w + v1.w*x7.w;
  }
  float4 h = *(const float4*)(Hout + (size_t)row*DD + d4);
  float part = h.x*(h.x-acc.x) + h.y*(h.y-acc.y) + h.z*(h.z-acc.z) + h.w*(h.w-acc.w);
  #pragma unroll
  for (int o = 32; o > 0; o >>= 1) part += __shfl_xor(part, o, 64);
  __shared__ float red[4];
  if ((t & 63) == 0) red[t >> 6] = part;
  __syncthreads();
  if (t == 0) partial[blockIdx.x] = red[0] + red[1] + red[2] + red[3];
}

// ---------------- final reduce: lap_smooth + orth_loss ----------------
__global__ void k_red(const float* __restrict__ ws, float* __restrict__ out) {
  const float* partial = ws + OFF_PART;
  int t = threadIdx.x;  // 256 threads, 1024 partials
  float4 p = *(const float4*)(partial + t*4);
  float s = p.x + p.y + p.z + p.w;
  #pragma unroll
  for (int o = 32; o > 0; o >>= 1) s += __shfl_xor(s, o, 64);
  __shared__ float red[4];
  if ((t & 63) == 0) red[t >> 6] = s;
  __syncthreads();
  if (t == 0) {
    out[1] = red[0] + red[1] + red[2] + red[3];   // lap_smooth
    const float* op = ws + OFF_ORTH;
    out[0] = op[0] + op[1] + op[2] + op[3] + op[4] + op[5];  // orth_loss
  }
}

extern "C" void kernel_launch(void* const* d_in, const int* in_sizes, int n_in,
                              void* d_out, int out_size, void* d_ws, size_t ws_size,
                              hipStream_t stream) {
  const float* H   = (const float*)d_in[0];
  const float* A   = (const float*)d_in[1];
  // d_in[2] (adj_mask) and d_in[3] (L) are never read: mask == (A != 0), L == I - A
  const float* U   = (const float*)d_in[4];
  const float* ll  = (const float*)d_in[5];
  const float* hw  = (const float*)d_in[6];
  const float* thr = (const float*)d_in[7];
  const float* gma = (const float*)d_in[8];
  const float* bta = (const float*)d_in[9];
  float* out = (float*)d_out;
  float* ws  = (float*)d_ws;
  int* nnz   = (int*)(ws + OFF_NNZ);
  int* cols  = (int*)(ws + OFF_COLS);
  float* vals = ws + OFF_VALS;
  float* Y = ws + OFF_Y;

  // 1: CSR scan + FUSED H1 = A@H, Y0 = H@U0, Y1 = H1@U1 + orth partials + scalars/M-init
  k_csr_prep<<<NN/2 + 7, 256, 0, stream>>>(A, nnz, cols, vals, hw, ll, U, ws, out, H);
  // 2: H2 = A@H1, Y2 = H2@U2 + gram(k=0,1) extra blocks (Y0/Y1 ready; no overlap with M/Y2)
  k_spmvy<<<NN/4 + 64, 256, 0, stream>>>(ws + OFF_H1, ws + OFF_H2, nnz, cols, vals,
                                         nullptr, nullptr, U + (size_t)2*DD*RR, Y + (size_t)2*NN*RR,
                                         Y, ws + OFF_M);
  // 3: gram k=2 (needs Y2) + H3 = A@H2 extra blocks (fills the otherwise-idle GPU)
  k_gram2h3<<<32 + NN/4, 256, 0, stream>>>(Y + (size_t)2*NN*RR, ws + OFF_M + 2*RR*RR,
                                           nnz, cols, vals, ws + OFF_H2, ws + OFF_H3);
  // 4: Minv = M^{-1} (rolled wave-synchronous LDS GJ) + W_k = U_k @ Minv_k (distributed)
  dim3 ggj(KK, 4);
  k_gj<<<ggj, 256, 0, stream>>>(ws + OFF_M, ws + OFF_MINV, U, ws + OFF_W);
  // 5: attention (pure; H3 moved to dispatch 3)
  dim3 gattn(NN/4, KK);
  k_attn<<<gattn, 256, 0, stream>>>(Y, ws + OFF_MINV, ws + OFF_P, nnz, cols);
  // 6: epilogue (grad = W @ vsum)
  k_epi<<<NN/8, 256, 0, stream>>>(H, ws, thr, gma, bta, out);
  // 7: lap_smooth partials
  k_lapsm<<<NN/4, 256, 0, stream>>>(out, nnz, cols, vals, ws + OFF_PART);
  // 8: final scalar reduce
  k_red<<<1, 256, 0, stream>>>(ws, out + NN*DD);
  // out layout: [H_out (NN*DD)] [orth_loss] [lap_smooth] [w0 w1 w2]
}

// Round 12
// 279.686 us; speedup vs baseline: 1.0182x; 1.0182x over previous
//
#include <hip/hip_runtime.h>
#include <math.h>

#define NN 4096
#define DD 256
#define KK 3
#define RR 32
#define MAXNNZ 128

static constexpr float ETA    = 0.5f;
static constexpr float COEFF  = 0.03125f;   // R/(N*eps^2) = 32/(4096*0.25)
static constexpr float LN_EPSF = 1e-5f;

// workspace layout (float offsets)
#define OFF_H1   0
#define OFF_H2   (NN*DD)
#define OFF_H3   (2*NN*DD)
#define OFF_Y    (3*NN*DD)
#define OFF_P    (OFF_Y + KK*NN*RR)
#define OFF_M    (OFF_P + KK*NN*RR)
#define OFF_MINV (OFF_M + KK*RR*RR)
#define OFF_SCAL (OFF_MINV + KK*RR*RR)   // w[3], laps[3]
#define OFF_NNZ  (OFF_SCAL + 8)          // N ints
#define OFF_COLS (OFF_NNZ + NN)          // N*MAXNNZ ints
#define OFF_VALS (OFF_COLS + NN*MAXNNZ)  // N*MAXNNZ floats
#define OFF_PART (OFF_VALS + NN*MAXNNZ)  // NN/4 floats (lap_smooth partials)
#define OFF_ORTH (OFF_PART + NN/4)       // 6 floats (orth partials)
#define OFF_W    (OFF_ORTH + 8)          // KK*DD*RR floats: W_k = U_k @ Minv_k

// ---------------- dispatch 1: CSR extract + FUSED H1/Y0/Y1 + orth + prep ----------------
// R8: A-scan is pattern-floor-bound (~41us regardless of structure), so this kernel does
// more per byte: CSR -> LDS -> H1 = A@H -> Y0/Y1 projections, removing a whole spmv
// dispatch and its 4MB CSR re-read. H-gather latency overlaps OTHER blocks' A-streams
// within the dispatch. Phase 3 stays waves 0/2 only (R10: splitting the row gather
// across 2 waves reassociated the H1 sum and DOUBLED absmax for zero perf).
__global__ __launch_bounds__(256, 4)
void k_csr_prep(const float* __restrict__ A, int* __restrict__ nnz,
                int* __restrict__ cols, float* __restrict__ vals,
                const float* __restrict__ hw, const float* __restrict__ ll,
                const float* __restrict__ U,
                float* __restrict__ ws, float* __restrict__ out,
                const float* __restrict__ H) {
  int b = blockIdx.x;
  int t = threadIdx.x;
  if (b >= NN/2) {
    int p = b - NN/2;
    if (p == 6) {
      if (t == 0) {
        float m = fmaxf(fmaxf(hw[0], hw[1]), hw[2]);
        float e0 = expf(hw[0]-m), e1 = expf(hw[1]-m), e2 = expf(hw[2]-m);
        float s = e0 + e1 + e2;
        float w0 = e0/s, w1 = e1/s, w2 = e2/s;
        ws[OFF_SCAL+0] = w0; ws[OFF_SCAL+1] = w1; ws[OFF_SCAL+2] = w2;
        for (int k = 0; k < KK; ++k) {
          float x = ll[k];
          ws[OFF_SCAL+3+k] = (x > 20.f) ? x : log1pf(expf(x));
        }
        out[NN*DD + 2] = w0; out[NN*DD + 3] = w1; out[NN*DD + 4] = w2;  // w output
      }
      for (int idx = t; idx < KK*RR*RR; idx += 256) {
        int rr2 = idx % (RR*RR);
        ws[OFF_M + idx] = ((rr2 / RR) == (rr2 % RR)) ? 1.f : 0.f;
      }
      return;
    }
    // orth pair p: thread owns 4 cells (same col bb, rows a0, a0+8, a0+16, a0+24)
    int k = (p < 3) ? 0 : ((p < 5) ? 1 : 2);
    int l = (p < 3) ? p : ((p < 5) ? p - 2 : 2);
    int a0 = t >> 5, bb = t & 31;
    float s0 = 0.f, s1 = 0.f, s2 = 0.f, s3 = 0.f;
    for (int dd = 0; dd < DD; ++dd) {
      float ul = U[(size_t)l*DD*RR + dd*RR + bb];
      const float* uk = U + (size_t)k*DD*RR + dd*RR;
      s0 += uk[a0]      * ul;
      s1 += uk[a0 + 8]  * ul;
      s2 += uk[a0 + 16] * ul;
      s3 += uk[a0 + 24] * ul;
    }
    if (k == l && bb == a0)      s0 -= 1.f;
    if (k == l && bb == a0 + 8)  s1 -= 1.f;
    if (k == l && bb == a0 + 16) s2 -= 1.f;
    if (k == l && bb == a0 + 24) s3 -= 1.f;
    float sq = s0*s0 + s1*s1 + s2*s2 + s3*s3;
    #pragma unroll
    for (int o = 32; o > 0; o >>= 1) sq += __shfl_xor(sq, o, 64);
    __shared__ float red[4];
    if ((t & 63) == 0) red[t >> 6] = sq;
    __syncthreads();
    if (t == 0) ws[OFF_ORTH + p] = red[0] + red[1] + red[2] + red[3];
    return;
  }
  // ---- phase 1: scan. wave w = (row r = w>>1, half h2 = w&1). Half = 2048 cols. ----
  int w = t >> 6, lane = t & 63;
  int r = w >> 1, h2 = w & 1;
  int i = b * 2 + r;
  __shared__ int   cbuf[2][2][MAXNNZ];
  __shared__ float vbuf[2][2][MAXNNZ];
  __shared__ int   csr_c[2][MAXNNZ];
  __shared__ float csr_v[2][MAXNNZ];
  __shared__ int   cnts[4];
  __shared__ int   nnzs[2];
  __shared__ float Hs[2][2][DD];   // [row][0=own(H),1=acc(H1)][dim]
  const float4* row4 = (const float4*)(A + (size_t)i * NN);
  float4 vv[8];
  #pragma unroll
  for (int it = 0; it < 8; ++it) vv[it] = row4[h2*512 + it*64 + lane];  // 8 loads in flight
  unsigned long long lower = lane ? (~0ull >> (64 - lane)) : 0ull;
  int base = 0;
  #pragma unroll
  for (int it = 0; it < 8; ++it) {
    float4 v = vv[it];
    int jb = (h2*512 + it*64 + lane) * 4;
    unsigned long long mx = __ballot(v.x != 0.f);
    unsigned long long my = __ballot(v.y != 0.f);
    unsigned long long mz = __ballot(v.z != 0.f);
    unsigned long long mw = __ballot(v.w != 0.f);
    int before = __popcll(mx & lower) + __popcll(my & lower)
               + __popcll(mz & lower) + __popcll(mw & lower);
    int p0 = base + before;
    int bx = (mx >> lane) & 1, by = (my >> lane) & 1, bz = (mz >> lane) & 1;
    if (v.x != 0.f && p0 < MAXNNZ)  { cbuf[r][h2][p0] = jb;   vbuf[r][h2][p0] = v.x; }
    int p1 = p0 + bx;
    if (v.y != 0.f && p1 < MAXNNZ)  { cbuf[r][h2][p1] = jb+1; vbuf[r][h2][p1] = v.y; }
    int p2 = p1 + by;
    if (v.z != 0.f && p2 < MAXNNZ)  { cbuf[r][h2][p2] = jb+2; vbuf[r][h2][p2] = v.z; }
    int p3 = p2 + bz;
    if (v.w != 0.f && p3 < MAXNNZ)  { cbuf[r][h2][p3] = jb+3; vbuf[r][h2][p3] = v.w; }
    base += __popcll(mx) + __popcll(my) + __popcll(mz) + __popcll(mw);
  }
  if (lane == 0) cnts[w] = base < MAXNNZ ? base : MAXNNZ;
  __syncthreads();
  // ---- phase 2: merge to global CSR AND LDS CSR ----
  {
    int rr = t >> 7, e0 = t & 127;
    int ii = b * 2 + rr;
    int n0 = cnts[rr*2], n1 = cnts[rr*2 + 1];
    int n = n0 + n1; if (n > MAXNNZ) n = MAXNNZ;
    int npad = (n + 7) & ~7;
    for (int e = e0; e < npad; e += 128) {
      int c; float v;
      if (e < n) {
        if (e < n0) { c = cbuf[rr][0][e];      v = vbuf[rr][0][e]; }
        else        { c = cbuf[rr][1][e - n0]; v = vbuf[rr][1][e - n0]; }
      } else { c = ii; v = 0.f; }
      cols[ii*MAXNNZ + e] = c;
      vals[ii*MAXNNZ + e] = v;
      csr_c[rr][e] = c;
      csr_v[rr][e] = v;
    }
    if (e0 == 0) { nnz[ii] = n; nnzs[rr] = n; }
  }
  __syncthreads();
  // ---- phase 3: H1 = A@H for this block's 2 rows (waves 0,2; CSR from LDS) ----
  float* H1 = ws + OFF_H1;
  if ((w & 1) == 0) {
    int rI = w >> 1;
    int row = b * 2 + rI;
    int d4 = lane * 4;
    int n2 = nnzs[rI], npad2 = (n2 + 7) & ~7;
    float4 acc = {0.f, 0.f, 0.f, 0.f};
    float4 own = {0.f, 0.f, 0.f, 0.f};
    for (int e0i = 0; e0i < npad2; e0i += 8) {
      int4 c0 = *(const int4*)&csr_c[rI][e0i];
      int4 c1 = *(const int4*)&csr_c[rI][e0i + 4];
      float4 v0 = *(const float4*)&csr_v[rI][e0i];
      float4 v1 = *(const float4*)&csr_v[rI][e0i + 4];
      float4 x0 = *(const float4*)(H + (size_t)c0.x*DD + d4);
      float4 x1 = *(const float4*)(H + (size_t)c0.y*DD + d4);
      float4 x2 = *(const float4*)(H + (size_t)c0.z*DD + d4);
      float4 x3 = *(const float4*)(H + (size_t)c0.w*DD + d4);
      float4 x4 = *(const float4*)(H + (size_t)c1.x*DD + d4);
      float4 x5 = *(const float4*)(H + (size_t)c1.y*DD + d4);
      float4 x6 = *(const float4*)(H + (size_t)c1.z*DD + d4);
      float4 x7 = *(const float4*)(H + (size_t)c1.w*DD + d4);
      if (c0.x == row) own = x0;
      if (c0.y == row) own = x1;
      if (c0.z == row) own = x2;
      if (c0.w == row) own = x3;
      if (c1.x == row) own = x4;
      if (c1.y == row) own = x5;
      if (c1.z == row) own = x6;
      if (c1.w == row) own = x7;
      acc.x += v0.x*x0.x + v0.y*x1.x + v0.z*x2.x + v0.w*x3.x + v1.x*x4.x + v1.y*x5.x + v1.z*x6.x + v1.w*x7.x;
      acc.y += v0.x*x0.y + v0.y*x1.y + v0.z*x2.y + v0.w*x3.y + v1.x*x4.y + v1.y*x5.y + v1.z*x6.y + v1.w*x7.y;
      acc.z += v0.x*x0.z + v0.y*x1.z + v0.z*x2.z + v0.w*x3.z + v1.x*x4.z + v1.y*x5.z + v1.z*x6.z + v1.w*x7.z;
      acc.w += v0.x*x0.w + v0.y*x1.w + v0.z*x2.w + v0.w*x3.w + v1.x*x4.w + v1.y*x5.w + v1.z*x6.w + v1.w*x7.w;
    }
    *(float4*)(H1 + (size_t)row*DD + d4) = acc;
    *(float4*)&Hs[rI][0][d4] = own;
    *(float4*)&Hs[rI][1][d4] = acc;
  }
  __syncthreads();
  // ---- phase 4: projections. wave w -> (row w>>1, w&1 ? Y1=H1@U1 : Y0=H@U0) ----
  {
    int rI = w >> 1;
    int row = b * 2 + rI;
    int useAcc = w & 1;
    const float* Up = U + (size_t)useAcc*DD*RR;          // U0 or U1
    float* Yp = ws + OFF_Y + (size_t)useAcc*NN*RR;       // Y0 or Y1
    int c = lane & 31, h = lane >> 5;
    float part = 0.f;
    #pragma unroll 8
    for (int d = h*128; d < h*128 + 128; ++d) part += Hs[rI][useAcc][d] * Up[d*RR + c];
    part += __shfl_xor(part, 32, 64);
    if (h == 0) Yp[(size_t)row*RR + c] = part;
  }
}

// ---------------- 4-row sparse gather quad: acc = (A @ X)[row], own = X[row] ------------
__device__ __forceinline__ void spmv_quad(const float* __restrict__ X, int row, int lane,
                                          const int* __restrict__ nnz,
                                          const int* __restrict__ cols,
                                          const float* __restrict__ vals,
                                          float4& acc, float4& own) {
  int d4 = lane * 4;
  int n = nnz[row];
  int npad = (n + 7) & ~7;
  const int* ci = cols + row*MAXNNZ;
  const float* vi = vals + row*MAXNNZ;
  for (int e0 = 0; e0 < npad; e0 += 8) {
    int4 c0 = *(const int4*)(ci + e0);
    int4 c1 = *(const int4*)(ci + e0 + 4);
    float4 v0 = *(const float4*)(vi + e0);
    float4 v1 = *(const float4*)(vi + e0 + 4);
    float4 x0 = *(const float4*)(X + (size_t)c0.x*DD + d4);
    float4 x1 = *(const float4*)(X + (size_t)c0.y*DD + d4);
    float4 x2 = *(const float4*)(X + (size_t)c0.z*DD + d4);
    float4 x3 = *(const float4*)(X + (size_t)c0.w*DD + d4);
    float4 x4 = *(const float4*)(X + (size_t)c1.x*DD + d4);
    float4 x5 = *(const float4*)(X + (size_t)c1.y*DD + d4);
    float4 x6 = *(const float4*)(X + (size_t)c1.z*DD + d4);
    float4 x7 = *(const float4*)(X + (size_t)c1.w*DD + d4);
    if (c0.x == row) own = x0;
    if (c0.y == row) own = x1;
    if (c0.z == row) own = x2;
    if (c0.w == row) own = x3;
    if (c1.x == row) own = x4;
    if (c1.y == row) own = x5;
    if (c1.z == row) own = x6;
    if (c1.w == row) own = x7;
    acc.x += v0.x*x0.x + v0.y*x1.x + v0.z*x2.x + v0.w*x3.x + v1.x*x4.x + v1.y*x5.x + v1.z*x6.x + v1.w*x7.x;
    acc.y += v0.x*x0.y + v0.y*x1.y + v0.z*x2.y + v0.w*x3.y + v1.x*x4.y + v1.y*x5.y + v1.z*x6.y + v1.w*x7.y;
    acc.z += v0.x*x0.z + v0.y*x1.z + v0.z*x2.z + v0.w*x3.z + v1.x*x4.z + v1.y*x5.z + v1.z*x6.z + v1.w*x7.z;
    acc.w += v0.x*x0.w + v0.y*x1.w + v0.z*x2.w + v0.w*x3.w + v1.x*x4.w + v1.y*x5.w + v1.z*x6.w + v1.w*x7.w;
  }
}

// ---------------- sparse A @ X with optional fused subspace projections ----------------
__global__ void k_spmvy(const float* __restrict__ X, float* __restrict__ Hout,
                        const int* __restrict__ nnz, const int* __restrict__ cols,
                        const float* __restrict__ vals,
                        const float* __restrict__ Uo, float* __restrict__ Yo,
                        const float* __restrict__ Un, float* __restrict__ Yn) {
  int t = threadIdx.x;
  int r = t >> 6, lane = t & 63;
  int row = blockIdx.x * 4 + r;
  int d4 = lane * 4;
  float4 acc = {0.f, 0.f, 0.f, 0.f};
  float4 own = {0.f, 0.f, 0.f, 0.f};
  spmv_quad(X, row, lane, nnz, cols, vals, acc, own);
  *(float4*)(Hout + (size_t)row*DD + d4) = acc;
  if (!Uo && !Un) return;
  __shared__ float Hs[4][2][DD];
  *(float4*)&Hs[r][0][d4] = own;
  *(float4*)&Hs[r][1][d4] = acc;
  __syncthreads();
  int c = lane & 31, h = lane >> 5;
  if (Uo) {
    float part = 0.f;
    #pragma unroll 8
    for (int d = h*128; d < h*128 + 128; ++d) part += Hs[r][0][d] * Uo[d*RR + c];
    part += __shfl_xor(part, 32, 64);
    if (h == 0) Yo[(size_t)row*RR + c] = part;
  }
  if (Un) {
    float part = 0.f;
    #pragma unroll 8
    for (int d = h*128; d < h*128 + 128; ++d) part += Hs[r][1][d] * Un[d*RR + c];
    part += __shfl_xor(part, 32, 64);
    if (h == 0) Yn[(size_t)row*RR + c] = part;
  }
}

// ---------------- M_k += coeff * Y^T Y (M pre-inited to I) ----------------
__global__ __launch_bounds__(1024) void k_gram(const float* __restrict__ Y, float* __restrict__ M) {
  int k = blockIdx.y;
  __shared__ float Ys[128*RR];
  int t = threadIdx.x;
  const float* Yk = Y + (size_t)k*NN*RR + (size_t)blockIdx.x*128*RR;
  for (int idx = t; idx < 128*RR; idx += 1024) Ys[idx] = Yk[idx];
  __syncthreads();
  int a = t >> 5, b = t & 31;
  float s = 0.f;
  for (int i = 0; i < 128; ++i) s += Ys[i*RR + a] * Ys[i*RR + b];
  atomicAdd(&M[k*RR*RR + a*RR + b], COEFF * s);
}

// ---------------- 32x32 inverse: rolled wave-synchronous LDS Gauss-Jordan ----------------
// One wave, zero barriers in the loop, ~150-instr body (icache-friendly). Lane t owns
// column t of the augmented [M | I] in LDS. Per pivot p: batch-read all 32 factors
// B[r][p] as independent broadcast reads BEFORE any write (pipelined). Grid (KK, 4):
// inverse computed redundantly per block; W = U @ Minv epilogue distributed over 4 blocks.
__global__ __launch_bounds__(256) void k_gj(const float* __restrict__ M, float* __restrict__ Minv,
                                            const float* __restrict__ U, float* __restrict__ W) {
  int k = blockIdx.x;
  int g = blockIdx.y;
  int t = threadIdx.x;
  __shared__ float B[RR][2*RR + 1];   // augmented [M | I], pad col to break bank patterns
  for (int idx = t; idx < RR*2*RR; idx += 256) {
    int r = idx >> 6, c = idx & 63;
    B[r][c] = (c < RR) ? M[k*RR*RR + r*RR + c] : ((c - RR == r) ? 1.f : 0.f);
  }
  __syncthreads();
  if (t < 64) {
    for (int p = 0; p < RR; ++p) {
      float rd = 1.f / B[p][p];       // broadcast read, all lanes same addr
      float pb = B[p][t] * rd;
      float f[RR];
      #pragma unroll
      for (int r = 0; r < RR; ++r) f[r] = B[r][p];   // 32 independent broadcast reads
      B[p][t] = pb;
      #pragma unroll
      for (int r = 0; r < RR; ++r) {
        if (r == p) continue;
        B[r][t] -= f[r] * pb;         // independent RMWs across r, pipelined
      }
    }
  }
  __syncthreads();
  if (g == 0)
    for (int idx = t; idx < RR*RR; idx += 256)
      Minv[k*RR*RR + idx] = B[idx >> 5][RR + (idx & 31)];
  // W_k[d][r] = sum_a U_k[d][a] * Minv[a][r], slice d in [g*64, g*64+64)
  for (int e = 0; e < 8; ++e) {
    int idx = t + e*256;              // 0..2047 within slice
    int d = g*64 + (idx >> 5), rr2 = idx & 31;
    const float* ud = U + (size_t)k*DD*RR + (size_t)d*RR;
    float s = 0.f;
    #pragma unroll
    for (int a = 0; a < RR; ++a) s += ud[a] * B[a][RR + rr2];
    W[(size_t)k*DD*RR + (size_t)d*RR + rr2] = s;
  }
}

// ---------------- sparse masked attention: P_i = sum_j alpha_ij Y_j (vsum only) ----------
// 4 rows per 256-thread block share one Minv LDS load. Pass 1 uses 4 lanes per neighbor
// AND spills each neighbor row to an LDS cache Yc[w][e][.] (stride 33: both write and
// read <=2-way bank aliasing -> free per m136). Pass 2 reads the cache instead of
// re-gathering the same rows from L2. Values/order bitwise-identical to uncached.
// EXTRA BLOCKS (x >= NN/4, y == 0): H3 = A @ H2 spmv rides in this dispatch — H3 is
// consumed only by k_epi; riding here keeps it OFF the gj/attn critical path (R11:
// putting it before gj regressed 4us).
__global__ __launch_bounds__(256) void k_attn(const float* __restrict__ Y, const float* __restrict__ Minv,
                       float* __restrict__ P, const int* __restrict__ nnz,
                       const int* __restrict__ cols, const float* __restrict__ vals,
                       const float* __restrict__ H2, float* __restrict__ H3) {
  int k = blockIdx.y;
  int t = threadIdx.x;
  int w = t >> 6, lane = t & 63;       // wave w owns row i
  if (blockIdx.x >= NN/4) {
    if (k != 0) return;
    int row = (blockIdx.x - NN/4) * 4 + w;
    float4 acc = {0.f, 0.f, 0.f, 0.f};
    float4 own;
    spmv_quad(H2, row, lane, nnz, cols, vals, acc, own);
    *(float4*)(H3 + (size_t)row*DD + lane*4) = acc;
    return;
  }
  int i = blockIdx.x * 4 + w;
  const float* Yk = Y + (size_t)k*NN*RR;
  __shared__ float Mi[RR*RR];          // Minv (symmetric), shared by all 4 rows
  __shared__ float Yi[4][RR];
  __shared__ float qv[4][RR];
  __shared__ float sc[4][MAXNNZ];
  __shared__ float Yc[4][32][RR + 1];  // neighbor-row cache (e < 32), wave-private slices
  for (int idx = t; idx < RR*RR; idx += 256) Mi[idx] = Minv[k*RR*RR + idx];
  if (lane < RR) Yi[w][lane] = Yk[(size_t)i*RR + lane];
  sc[w][lane] = -1e30f; sc[w][lane+64] = -1e30f;
  __syncthreads();
  if (lane < RR) {
    float s = 0.f;
    #pragma unroll 8
    for (int a = 0; a < RR; ++a) s += Mi[a*RR + lane] * Yi[w][a];   // symmetric: col == row
    qv[w][lane] = s;
  }
  // wave-private from here on; no block barriers.
  int g = lane >> 2, a4 = lane & 3;
  const float* qq = &qv[w][8*a4];
  float q0 = qq[0], q1 = qq[1], q2 = qq[2], q3 = qq[3];
  float q4 = qq[4], q5 = qq[5], q6 = qq[6], q7 = qq[7];
  int n = nnz[i], npad = (n + 7) & ~7;
  const int* ci = cols + i*MAXNNZ;
  for (int e0 = 0; e0 < npad; e0 += 16) {
    int e = e0 + g;
    int ee = (e < npad) ? e : 0;
    int col = ci[ee];
    const float4* yr = (const float4*)(Yk + (size_t)col*RR + 8*a4);
    float4 y0 = yr[0], y1 = yr[1];
    if (e < 32) {                      // spill row quarter to cache (always true in practice)
      *(float4*)&Yc[w][e][8*a4]     = y0;
      *(float4*)&Yc[w][e][8*a4 + 4] = y1;
    }
    float s = y0.x*q0 + y0.y*q1 + y0.z*q2 + y0.w*q3
            + y1.x*q4 + y1.y*q5 + y1.z*q6 + y1.w*q7;
    s += __shfl_xor(s, 1, 64);
    s += __shfl_xor(s, 2, 64);
    if (a4 == 0 && e < npad) sc[w][e] = (e < n) ? s : -1e30f;
  }
  float s0 = sc[w][lane], s1 = sc[w][lane+64];
  float m = fmaxf(s0, s1);
  #pragma unroll
  for (int o = 32; o > 0; o >>= 1) m = fmaxf(m, __shfl_xor(m, o, 64));
  float e0v = expf(s0 - m), e1v = expf(s1 - m);
  sc[w][lane] = e0v; sc[w][lane+64] = e1v;
  float l = e0v + e1v;
  #pragma unroll
  for (int o = 32; o > 0; o >>= 1) l += __shfl_xor(l, o, 64);
  float linv = 1.f / l;
  int c = lane & 31, h = lane >> 5;
  float acc = 0.f;
  int lim = npad < 32 ? npad : 32;
  for (int e = h; e < lim; e += 2) acc += sc[w][e] * Yc[w][e][c];        // LDS, conflict-free
  for (int e = 32 + h; e < npad; e += 2) acc += sc[w][e] * Yk[(size_t)ci[e]*RR + c];  // rare tail
  acc += __shfl_xor(acc, 32, 64);
  if (lane < RR) P[(size_t)k*NN*RR + (size_t)i*RR + lane] = acc * linv;
}

// ---------------- fused epilogue (grad = W @ vsum) ----------------
__global__ void k_epi(const float* __restrict__ H0, const float* __restrict__ ws,
                      const float* __restrict__ thr,
                      const float* __restrict__ gma, const float* __restrict__ bta,
                      float* __restrict__ out) {
  __shared__ float Us[DD][RR+1];
  __shared__ float Ps[8][KK*RR];
  int t = threadIdx.x;
  int ty = t >> 5, tx = t & 31;
  int row0 = blockIdx.x * 8;
  const float* P    = ws + OFF_P;
  const float* scal = ws + OFF_SCAL;
  const float* W    = ws + OFF_W;
  for (int idx = t; idx < 8*KK*RR; idx += 256) {
    int rl = idx / (KK*RR), kr = idx % (KK*RR);
    int k = kr / RR, rr2 = kr % RR;
    Ps[rl][kr] = P[(size_t)k*NN*RR + (size_t)(row0+rl)*RR + rr2];
  }
  float lp0 = scal[3], lp1 = scal[4], lp2 = scal[5];
  float gacc[8];
  #pragma unroll
  for (int j = 0; j < 8; ++j) gacc[j] = 0.f;
  for (int k = 0; k < KK; ++k) {
    __syncthreads();
    // float4 W staging (2048 float4s per k, 8 per thread)
    for (int idx = t; idx < DD*RR/4; idx += 256) {
      float4 w4 = *(const float4*)(W + (size_t)k*DD*RR + (size_t)idx*4);
      int d = (idx*4) >> 5, c = (idx*4) & 31;
      Us[d][c] = w4.x; Us[d][c+1] = w4.y; Us[d][c+2] = w4.z; Us[d][c+3] = w4.w;
    }
    __syncthreads();
    float wk = scal[k];
    #pragma unroll
    for (int j = 0; j < 8; ++j) {
      int d = tx + 32*j;
      float s = 0.f;
      #pragma unroll
      for (int rr2 = 0; rr2 < RR; ++rr2) s += Ps[ty][k*RR + rr2] * Us[d][rr2];
      gacc[j] += wk * s;
    }
  }
  int i = row0 + ty;
  const float* H1 = ws + OFF_H1;
  const float* H2 = ws + OFF_H2;
  const float* H3 = ws + OFF_H3;
  float v[8]; float sum = 0.f, sumsq = 0.f;
  #pragma unroll
  for (int j = 0; j < 8; ++j) {
    int d = tx + 32*j;
    size_t idx = (size_t)i*DD + d;
    float h0 = H0[idx], h1 = H1[idx], h2 = H2[idx], h3 = H3[idx];
    float lap = lp0*(h0-h1) + lp1*(h1-h2) + lp2*(h2-h3);
    float hf = h0 + ETA*gacc[j] - ETA*lap;
    float a = fabsf(hf) - thr[d];
    float sft = (a > 0.f) ? copysignf(a, hf) : 0.f;
    float x = sft + h0;
    v[j] = x; sum += x; sumsq += x*x;
  }
  #pragma unroll
  for (int o = 16; o > 0; o >>= 1) {
    sum   += __shfl_xor(sum, o, 32);
    sumsq += __shfl_xor(sumsq, o, 32);
  }
  float mu  = sum * (1.f/DD);
  float var = sumsq * (1.f/DD) - mu*mu;
  float inv = rsqrtf(var + LN_EPSF);
  #pragma unroll
  for (int j = 0; j < 8; ++j) {
    int d = tx + 32*j;
    out[(size_t)i*DD + d] = (v[j] - mu) * inv * gma[d] + bta[d];
  }
}

// ---------------- lap_smooth partials (no fences, no atomics) ----------------
__global__ void k_lapsm(const float* __restrict__ Hout, const int* __restrict__ nnz,
                        const int* __restrict__ cols, const float* __restrict__ vals,
                        float* __restrict__ partial) {
  int t = threadIdx.x;
  int row = blockIdx.x * 4 + (t >> 6);
  int d4 = (t & 63) * 4;
  int n = nnz[row];
  int npad = (n + 7) & ~7;
  const int* ci = cols + row*MAXNNZ;
  const float* vi = vals + row*MAXNNZ;
  float4 acc = {0.f, 0.f, 0.f, 0.f};
  for (int e0 = 0; e0 < npad; e0 += 8) {
    int4 c0 = *(const int4*)(ci + e0);
    int4 c1 = *(const int4*)(ci + e0 + 4);
    float4 v0 = *(const float4*)(vi + e0);
    float4 v1 = *(const float4*)(vi + e0 + 4);
    float4 x0 = *(const float4*)(Hout + (size_t)c0.x*DD + d4);
    float4 x1 = *(const float4*)(Hout + (size_t)c0.y*DD + d4);
    float4 x2 = *(const float4*)(Hout + (size_t)c0.z*DD + d4);
    float4 x3 = *(const float4*)(Hout + (size_t)c0.w*DD + d4);
    float4 x4 = *(const float4*)(Hout + (size_t)c1.x*DD + d4);
    float4 x5 = *(const float4*)(Hout + (size_t)c1.y*DD + d4);
    float4 x6 = *(const float4*)(Hout + (size_t)c1.z*DD + d4);
    float4 x7 = *(const float4*)(Hout + (size_t)c1.w*DD + d4);
    acc.x += v0.x*x0.x + v0.y*x1.x + v0.z*x2.x + v0.w*x3.x + v1.x*x4.x + v1.y*x5.x + v1.z*x6.x + v1.w*x7.x;
    acc.y += v0.x*x0.y + v0.y*x1.y + v0.z*x2.y + v0.w*x3.y + v1.x*x4.y + v1.y*x5.y + v1.z*x6.y + v1.w*x7.y;
    acc.z += v0.x*x0.z + v0.y*x1.z + v0.z*x2.z + v0.w*x3.z + v1.x*x4.z + v1.y*x5.z + v1.z*x6.z + v1.w*x7.z;
    acc.w += v0.x*x0.w + v0.y*x1.w + v0.z*x2.w + v0.w*x3.w + v1.x*x4.w + v1.y*x5.w + v1.z*x6.w + v1.w*x7.w;
  }
  float4 h = *(const float4*)(Hout + (size_t)row*DD + d4);
  float part = h.x*(h.x-acc.x) + h.y*(h.y-acc.y) + h.z*(h.z-acc.z) + h.w*(h.w-acc.w);
  #pragma unroll
  for (int o = 32; o > 0; o >>= 1) part += __shfl_xor(part, o, 64);
  __shared__ float red[4];
  if ((t & 63) == 0) red[t >> 6] = part;
  __syncthreads();
  if (t == 0) partial[blockIdx.x] = red[0] + red[1] + red[2] + red[3];
}

// ---------------- final reduce: lap_smooth + orth_loss ----------------
__global__ void k_red(const float* __restrict__ ws, float* __restrict__ out) {
  const float* partial = ws + OFF_PART;
  int t = threadIdx.x;  // 256 threads, 1024 partials
  float4 p = *(const float4*)(partial + t*4);
  float s = p.x + p.y + p.z + p.w;
  #pragma unroll
  for (int o = 32; o > 0; o >>= 1) s += __shfl_xor(s, o, 64);
  __shared__ float red[4];
  if ((t & 63) == 0) red[t >> 6] = s;
  __syncthreads();
  if (t == 0) {
    out[1] = red[0] + red[1] + red[2] + red[3];   // lap_smooth
    const float* op = ws + OFF_ORTH;
    out[0] = op[0] + op[1] + op[2] + op[3] + op[4] + op[5];  // orth_loss
  }
}

extern "C" void kernel_launch(void* const* d_in, const int* in_sizes, int n_in,
                              void* d_out, int out_size, void* d_ws, size_t ws_size,
                              hipStream_t stream) {
  const float* H   = (const float*)d_in[0];
  const float* A   = (const float*)d_in[1];
  // d_in[2] (adj_mask) and d_in[3] (L) are never read: mask == (A != 0), L == I - A
  const float* U   = (const float*)d_in[4];
  const float* ll  = (const float*)d_in[5];
  const float* hw  = (const float*)d_in[6];
  const float* thr = (const float*)d_in[7];
  const float* gma = (const float*)d_in[8];
  const float* bta = (const float*)d_in[9];
  float* out = (float*)d_out;
  float* ws  = (float*)d_ws;
  int* nnz   = (int*)(ws + OFF_NNZ);
  int* cols  = (int*)(ws + OFF_COLS);
  float* vals = ws + OFF_VALS;
  float* Y = ws + OFF_Y;

  // 1: CSR scan + FUSED H1 = A@H, Y0 = H@U0, Y1 = H1@U1 + orth partials + scalars/M-init
  k_csr_prep<<<NN/2 + 7, 256, 0, stream>>>(A, nnz, cols, vals, hw, ll, U, ws, out, H);
  // 2: H2 = A@H1, Y2 = H2@U2
  k_spmvy<<<NN/4, 256, 0, stream>>>(ws + OFF_H1, ws + OFF_H2, nnz, cols, vals,
                                    nullptr, nullptr, U + (size_t)2*DD*RR, Y + (size_t)2*NN*RR);
  // 3: M += coeff * Y^T Y  (only needs Y, not H3)
  dim3 g32(NN/128, KK);
  k_gram<<<g32, 1024, 0, stream>>>(Y, ws + OFF_M);
  // 4: Minv = M^{-1} (rolled wave-synchronous LDS GJ) + W_k = U_k @ Minv_k (distributed)
  dim3 ggj(KK, 4);
  k_gj<<<ggj, 256, 0, stream>>>(ws + OFF_M, ws + OFF_MINV, U, ws + OFF_W);
  // 5: attention + H3 = A@H2 as extra blocks (overlapped; H3 consumed only by k_epi)
  dim3 gattn(NN/4 + NN/4, KK);
  k_attn<<<gattn, 256, 0, stream>>>(Y, ws + OFF_MINV, ws + OFF_P, nnz, cols, vals,
                                    ws + OFF_H2, ws + OFF_H3);
  // 6: epilogue (grad = W @ vsum)
  k_epi<<<NN/8, 256, 0, stream>>>(H, ws, thr, gma, bta, out);
  // 7: lap_smooth partials
  k_lapsm<<<NN/4, 256, 0, stream>>>(out, nnz, cols, vals, ws + OFF_PART);
  // 8: final scalar reduce
  k_red<<<1, 256, 0, stream>>>(ws, out + NN*DD);
  // out layout: [H_out (NN*DD)] [orth_loss] [lap_smooth] [w0 w1 w2]
}